// Round 4
// baseline (85.212 us; speedup 1.0000x reference)
//
#include <hip/hip_runtime.h>

#define NW 10

typedef float v2f __attribute__((ext_vector_type(2)));
typedef unsigned u32x2 __attribute__((ext_vector_type(2)));

// DPP: quad_perm xor1=0xB1, xor2=0x4E, xor3=0x1B; row_ror:8 (xor8 within 16) = 0x128;
// row_half_mirror (xor7 within 8) = 0x141
template<int CTRL>
__device__ __forceinline__ float fdpp(float v) {
    return __int_as_float(__builtin_amdgcn_mov_dpp(__float_as_int(v), CTRL, 0xF, 0xF, true));
}
// ds_swizzle BitMode: xor4=0x101F, xor16=0x401F
template<int PAT>
__device__ __forceinline__ float fswz(float v) {
    return __int_as_float(__builtin_amdgcn_ds_swizzle(__float_as_int(v), PAT));
}
__device__ __forceinline__ float fbperm(int addr, float v) {
    return __int_as_float(__builtin_amdgcn_ds_bpermute(addr, __float_as_int(v)));
}

// psumK(v) = v[d] + v[d^K], pure VALU via gfx950 permlane{16,32}_swap builtins.
// With both operands = v, the two results are {dup-lo, dup-hi} in SOME order
// (direction-independent), so their sum is v + v^K on every lane. Compiler
// handles the permlane write hazards and operand copies (inline asm did not —
// that was round 3's corruption).
__device__ __forceinline__ float psum16(float v) {
#if __has_builtin(__builtin_amdgcn_permlane16_swap)
    u32x2 r = __builtin_amdgcn_permlane16_swap(__float_as_uint(v), __float_as_uint(v), false, false);
    return __uint_as_float(r.x) + __uint_as_float(r.y);
#else
    return v + fswz<0x401F>(v);
#endif
}
__device__ __forceinline__ float psum32(float v) {
#if __has_builtin(__builtin_amdgcn_permlane32_swap)
    u32x2 r = __builtin_amdgcn_permlane32_swap(__float_as_uint(v), __float_as_uint(v), false, false);
    return __uint_as_float(r.x) + __uint_as_float(r.y);
#else
    return v + __shfl_xor(v, 32, 64);
#endif
}

// ---------------- precompute: 7 folded diag tables (cs,sn) + 80 RY (cos,sin) ----
// Fold rule: D2 . P(D1 . s)[u] = (D2[u]*D1[P(u)])*s[P(u)], P(s)=s^(s>>1)^((s&1)*0x300).
// d<4 : T1[k=d]   = rz3_k(s)*rz2_k(P(s))       (applied post-perm)
// d<7 : T2[k=d-4] = rz0_{k+1}(s)*rz5_k(P(s))   (applied post-perm with x-phase)
// Table array index j: lane=j&63, r=(j>>6)&3, W=j>>8; entry is for position
// index s = (W<<8)|(lane<<2)|r.
__global__ void precompute_kernel(const float* __restrict__ params, float2* __restrict__ tab) {
    const int j = blockIdx.x * 256 + threadIdx.x;
    if (j < 7 * 1024) {
        const int d = j >> 10, jj = j & 1023;
        const int W = jj >> 8, lane = jj & 63, r = (jj >> 6) & 3;
        const int s = (W << 8) | (lane << 2) | r;
        const int q = s ^ (s >> 1) ^ ((s & 1) * 0x300);
        const float* thA;
        const float* thB;
        if (d < 4) {
            thA = params + (d * 6 + 3) * NW;          // rz3 of block d
            thB = params + (d * 6 + 2) * NW;          // rz2 of block d
        } else {
            const int k = d - 4;
            thA = params + ((k + 1) * 6 + 0) * NW;    // rz0 of block k+1
            thB = params + (k * 6 + 5) * NW;          // rz5 of block k
        }
        float ang = 0.f;
#pragma unroll
        for (int w = 0; w < NW; ++w) {
            ang += thA[w] * (((s >> (9 - w)) & 1) ? 0.5f : -0.5f);
            ang += thB[w] * (((q >> (9 - w)) & 1) ? 0.5f : -0.5f);
        }
        float sn, cs;
        __sincosf(ang, &sn, &cs);
        tab[j] = make_float2(cs, sn);
    } else if (j < 7 * 1024 + 80) {
        const int i = j - 7 * 1024;
        const int ry = i / NW, w = i % NW;
        const int k = ry >> 1, ii = ry & 1;
        const float* th = params + (k * 6 + (ii ? 4 : 1)) * NW;
        float sn, cs;
        __sincosf(0.5f * th[w], &sn, &cs);
        tab[7 * 1024 + i] = make_float2(cs, sn);
    }
}

// ---------------- main kernel: 1 wave = 1 sample, 16 amps/lane, 0 barriers ----
// Position bits of element index s (s = x9..x0):
//   x0=u0 x1=u1 (reg bits, m=1,2) | x2..x7 = lane bits l0..l5 | x8=u2 x9=u3 (reg, m=4,8)
// Wire w lives at position 9-w:
//   w9:u0  w8:u1  w7:l0(xor1 DPP)  w6:l1(xor2 DPP)  w5:l2(xor4 DPP-pair)
//   w4:l3(xor8 DPP)  w3:l4(xor16 permlane-sum)  w2:l5(xor32 permlane-sum)  w1:u2  w0:u3
// Perm y=P(x): y0=x0^x1, y1=x1^x2, ..., y7=x7^x8, y8=x8^x9^x0, y9=x9^x0.
// Gather for dest (u,lane):
//   src lane = (l0^l1)|((l1^l2)<<1)|((l2^l3)<<2)|((l3^l4)<<3)|((l4^l5)<<4)|((l5^u2)<<5)
//   src reg  = (u0^u1) | ((u1^d0)<<1) | ((u0^u2^u3)<<2) | ((u0^u3)<<3)
// where d0 is the CONSUMER's lane bit0. ds_bpermute is a pull, so each PROVIDER
// lane supplies the register its unique consumer wants: d0 = parity(lane bits) ^ u2.

#define DPP_STAGE(CTRL, CW, BIT) do {                                          \
    const float2 cw_ = (CW);                                                   \
    const float ss_ = (lane & (BIT)) ? cw_.y : -cw_.y;                         \
    _Pragma("unroll")                                                          \
    for (int u_ = 0; u_ < 16; ++u_) {                                          \
        v2f p_;                                                                \
        p_.x = fdpp<CTRL>(st[u_].x);                                           \
        p_.y = fdpp<CTRL>(st[u_].y);                                           \
        st[u_] = cw_.x * st[u_] + ss_ * p_;                                    \
    }                                                                          \
} while (0)

// xor4 = row_half_mirror (d^7) then quad_perm[3,2,1,0] (d^3): v[(d^3)^7] = v[d^4]
#define DPPX4_STAGE(CW, BIT) do {                                              \
    const float2 cw_ = (CW);                                                   \
    const float ss_ = (lane & (BIT)) ? cw_.y : -cw_.y;                         \
    _Pragma("unroll")                                                          \
    for (int u_ = 0; u_ < 16; ++u_) {                                          \
        v2f p_;                                                                \
        p_.x = fdpp<0x1B>(fdpp<0x141>(st[u_].x));                              \
        p_.y = fdpp<0x1B>(fdpp<0x141>(st[u_].y));                              \
        st[u_] = cw_.x * st[u_] + ss_ * p_;                                    \
    }                                                                          \
} while (0)

// butterfly via pair-sum: st' = c*st + ss*st[^K] = (c-ss)*st + ss*(st + st[^K])
#define PLSUM_STAGE(PSUM, CW, BIT) do {                                        \
    const float2 cw_ = (CW);                                                   \
    const float ss_ = (lane & (BIT)) ? cw_.y : -cw_.y;                         \
    const float al_ = cw_.x - ss_;                                             \
    _Pragma("unroll")                                                          \
    for (int u_ = 0; u_ < 16; ++u_) {                                          \
        v2f t_;                                                                \
        t_.x = PSUM(st[u_].x);                                                 \
        t_.y = PSUM(st[u_].y);                                                 \
        st[u_] = al_ * st[u_] + ss_ * t_;                                      \
    }                                                                          \
} while (0)

__global__ __launch_bounds__(256, 2) void qsim_kernel(const float* __restrict__ x,
                                                      const float2* __restrict__ tab,
                                                      float* __restrict__ out) {
    const int t    = threadIdx.x;
    const int W    = t >> 6;
    const int lane = t & 63;
    const int b    = blockIdx.x * 4 + W;           // one sample per wave
    const float2* ry_tab = tab + 7 * 1024;

    const int l0 = lane & 1, l1 = (lane >> 1) & 1, l2 = (lane >> 2) & 1,
              l3 = (lane >> 3) & 1, l4 = (lane >> 4) & 1, l5 = (lane >> 5) & 1;

    // perm bpermute addresses (byte addr = src_lane*4); pa1 = u2-flipped (bit5)
    const int lp = (l0 ^ l1) | ((l1 ^ l2) << 1) | ((l2 ^ l3) << 2)
                 | ((l3 ^ l4) << 3) | ((l4 ^ l5) << 4) | (l5 << 5);
    const int pa0 = lp << 2;
    const int pa1 = pa0 ^ 128;
    const int par = l0 ^ l1 ^ l2 ^ l3 ^ l4 ^ l5;   // consumer's d0 = par ^ u2

    v2f st[16];
    float2 xp[16];
    float2 tq[16];

    // x-phase e^{iA_x(s)} per register: ang(s) = -A/2 + sum over set bits of xv[wire]
    {
        const float* xb = x + b * NW;
        float xv[NW];
#pragma unroll
        for (int w = 0; w < NW; ++w) xv[w] = xb[w];
        float A = 0.f;
#pragma unroll
        for (int w = 0; w < NW; ++w) A += xv[w];
        float hb = -0.5f * A;
        if (l0) hb += xv[7];
        if (l1) hb += xv[6];
        if (l2) hb += xv[5];
        if (l3) hb += xv[4];
        if (l4) hb += xv[3];
        if (l5) hb += xv[2];
#pragma unroll
        for (int u = 0; u < 16; ++u) {
            float ang = hb;
            if (u & 1) ang += xv[9];
            if (u & 2) ang += xv[8];
            if (u & 4) ang += xv[1];
            if (u & 8) ang += xv[0];
            float sn, cs;
            __sincosf(ang, &sn, &cs);
            xp[u] = make_float2(cs, sn);
        }
    }

    // prefetch folded-diag entries; array index = lane | (u&3)<<6 | (u>>2)<<8
    auto pre = [&](int d) {
        const float2* tb = tab + (d << 10) + lane;
#pragma unroll
        for (int u = 0; u < 16; ++u)
            tq[u] = tb[((u & 3) << 6) | ((u >> 2) << 8)];
    };

    // analytic init: amp(s) = prod_w (bit_{9-w}(s) ? sin_w : cos_w), ridx 0
    auto initC = [&]() {
        const float2 r9 = ry_tab[9], r8 = ry_tab[8], r7 = ry_tab[7], r6 = ry_tab[6],
                     r5 = ry_tab[5], r4 = ry_tab[4], r3 = ry_tab[3], r2 = ry_tab[2],
                     r1 = ry_tab[1], r0 = ry_tab[0];
        float P6 = (l0 ? r7.y : r7.x) * (l1 ? r6.y : r6.x) * (l2 ? r5.y : r5.x)
                 * (l3 ? r4.y : r4.x) * (l4 ? r3.y : r3.x) * (l5 ? r2.y : r2.x);
#pragma unroll
        for (int u = 0; u < 16; ++u) {
            float v = P6 * ((u & 1) ? r9.y : r9.x) * ((u & 2) ? r8.y : r8.x)
                         * ((u & 4) ? r1.y : r1.x) * ((u & 8) ? r0.y : r0.x);
            st[u] = (v2f){v, 0.f};
        }
    };

    // register-local butterfly on reg-bit m
    auto bflyL = [&](float2 cw, int m) {
#pragma unroll
        for (int u = 0; u < 16; ++u)
            if (!(u & m)) {
                const int v = u | m;
                const v2f a = st[u];
                st[u] = cw.x * a - cw.y * st[v];
                st[v] = cw.y * a + cw.x * st[v];
            }
    };

    // full 10-wire RY, all intra-wave, no barriers, zero LDS-pipe ops
    auto ry = [&](int ridx) {
        const float2* rt = ry_tab + ridx * NW;
        bflyL(rt[9], 1);                 // w9: u0
        bflyL(rt[8], 2);                 // w8: u1
        bflyL(rt[1], 4);                 // w1: u2
        bflyL(rt[0], 8);                 // w0: u3
        DPP_STAGE(0xB1, rt[7], 1);       // w7: l0 xor1
        DPP_STAGE(0x4E, rt[6], 2);       // w6: l1 xor2
        DPPX4_STAGE(rt[5], 4);           // w5: l2 xor4 (DPP pair)
        DPP_STAGE(0x128, rt[4], 8);      // w4: l3 xor8
        PLSUM_STAGE(psum16, rt[3], 16);  // w3: l4 xor16 (permlane16_swap sum)
        PLSUM_STAGE(psum32, rt[2], 32);  // w2: l5 xor32 (permlane32_swap sum)
    };

    // perm gather fused with diag apply (mode1 also multiplies x-phase)
    auto permApply = [&](int mode) {
        v2f ns[16];
#pragma unroll
        for (int u = 0; u < 16; ++u) {
            const int u0 = u & 1, u1 = (u >> 1) & 1, u2 = (u >> 2) & 1, u3 = (u >> 3) & 1;
            const int a = (u0 ^ u1) | (u1 << 1) | ((u0 ^ u2 ^ u3) << 2) | ((u0 ^ u3) << 3);
            const v2f v = (par ^ u2) ? st[a ^ 2] : st[a];   // provider supplies for its consumer
            const int ad = u2 ? pa1 : pa0;
            ns[u].x = fbperm(ad, v.x);
            ns[u].y = fbperm(ad, v.y);
        }
#pragma unroll
        for (int u = 0; u < 16; ++u) {
            float cx = tq[u].x, cy = tq[u].y;
            if (mode) {
                const float tx = cx, ty = cy;
                cx = tx * xp[u].x - ty * xp[u].y;
                cy = tx * xp[u].y + ty * xp[u].x;
            }
            st[u] = (v2f){cx * ns[u].x - cy * ns[u].y,
                          cy * ns[u].x + cx * ns[u].y};
        }
    };

#pragma unroll 1
    for (int k = 0; k < 4; ++k) {
        pre(k);                          // T1[k]
        if (k == 0) initC();             // |0> -> ry(0) product state
        else        ry(2 * k);
        permApply(0);                    // perm + rz2.P * rz3
        if (k < 3) pre(4 + k);           // T2[k]
        ry(2 * k + 1);
        if (k < 3) permApply(1);         // perm + rz5.P * rz0(k+1) * enc(x)
        // k==3: rz5 pure phase (dropped); final perm folded into epilogue signs.
    }

    // ---- epilogue: out[w] = sum_e (-1)^{x_{9-w}(P^{-1}(e))} |st(e)|^2
    // P^{-1}: x8=y8^y9; x_j = y_j^...^y7^y8^y9 (j<=7); x9 = y0^...^y8.
    // Reg Walsh combos over (u0,u1,u2,u3) = (y0,y1,y8,y9):
    float pr[16];
#pragma unroll
    for (int u = 0; u < 16; ++u) pr[u] = st[u].x * st[u].x + st[u].y * st[u].y;

    float q0[4], q1[4], q2[4];
#pragma unroll
    for (int g = 0; g < 4; ++g) {
        const float a = pr[4 * g] + pr[4 * g + 1], bb = pr[4 * g + 2] + pr[4 * g + 3];
        const float c = pr[4 * g] - pr[4 * g + 1], d = pr[4 * g + 2] - pr[4 * g + 3];
        q0[g] = a + bb;   // sum over u0,u1
        q1[g] = a - bb;   // (-1)^{u1}
        q2[g] = c - d;    // (-1)^{u0^u1}
    }
    const float R23   = q0[0] - q0[1] - q0[2] + q0[3];   // (-1)^{u2^u3}
    const float R123  = q1[0] - q1[1] - q1[2] + q1[3];   // (-1)^{u1^u2^u3}
    const float R0123 = q2[0] - q2[1] - q2[2] + q2[3];   // (-1)^{u0^u1^u2^u3}
    const float R012  = q2[0] - q2[1] + q2[2] - q2[3];   // (-1)^{u0^u1^u2}

    // lane suffix parities over l5..l0 (= y7..y2)
    const int P5 = l5, P4 = l4 ^ P5, P3 = l3 ^ P4, P2 = l2 ^ P3, P1 = l1 ^ P2, P0 = l0 ^ P1;

    float acc[NW];
    acc[0] = P0 ? -R012 : R012;    // x9 = y0..y8
    acc[1] = R23;                  // x8 = y8^y9
    acc[2] = P5 ? -R23 : R23;      // x7 = y7^y8^y9
    acc[3] = P4 ? -R23 : R23;      // x6
    acc[4] = P3 ? -R23 : R23;      // x5
    acc[5] = P2 ? -R23 : R23;      // x4
    acc[6] = P1 ? -R23 : R23;      // x3
    acc[7] = P0 ? -R23 : R23;      // x2
    acc[8] = P0 ? -R123 : R123;    // x1 = y1..y9
    acc[9] = P0 ? -R0123 : R0123;  // x0 = y0..y9

#pragma unroll
    for (int w = 0; w < NW; ++w) {
        float a = acc[w];
        a += fdpp<0xB1>(a);
        a += fdpp<0x4E>(a);
        a += fswz<0x101F>(a);
        a += fdpp<0x128>(a);
        a = psum16(a);
        a = psum32(a);
        acc[w] = a;
    }
    if (lane == 0) {
        float2* o = (float2*)(out + b * NW);
        o[0] = make_float2(acc[0], acc[1]);
        o[1] = make_float2(acc[2], acc[3]);
        o[2] = make_float2(acc[4], acc[5]);
        o[3] = make_float2(acc[6], acc[7]);
        o[4] = make_float2(acc[8], acc[9]);
    }
}

extern "C" void kernel_launch(void* const* d_in, const int* in_sizes, int n_in,
                              void* d_out, int out_size, void* d_ws, size_t ws_size,
                              hipStream_t stream) {
    const float* x      = (const float*)d_in[0];   // (2048, 10)
    const float* params = (const float*)d_in[1];   // (4, 6, 10)
    float* out          = (float*)d_out;           // (1, 2048, 10)
    float2* tab         = (float2*)d_ws;           // 7*1024+80 float2 = 57 KB
    (void)in_sizes; (void)n_in; (void)out_size; (void)ws_size;
    precompute_kernel<<<29, 256, 0, stream>>>(params, tab);
    qsim_kernel<<<512, 256, 0, stream>>>(x, tab, out);
}

// Round 6
// 79.286 us; speedup vs baseline: 1.0747x; 1.0747x over previous
//
#include <hip/hip_runtime.h>

#define NW 10

typedef float v2f __attribute__((ext_vector_type(2)));

// DPP: quad_perm xor1=0xB1, xor2=0x4E; row_ror:8 (xor8 within 16) = 0x128
template<int CTRL>
__device__ __forceinline__ float fdpp(float v) {
    return __int_as_float(__builtin_amdgcn_mov_dpp(__float_as_int(v), CTRL, 0xF, 0xF, true));
}
// ds_swizzle BitMode: xor4=0x101F, xor16=0x401F
template<int PAT>
__device__ __forceinline__ float fswz(float v) {
    return __int_as_float(__builtin_amdgcn_ds_swizzle(__float_as_int(v), PAT));
}

// ---------------- precompute: 7 folded diag tables (cs,sn) + 80 RY (cos,sin) ----
// (unchanged, verified) Fold rule: D2.P(D1.s)[u] = (D2[u]*D1[P(u)])*s[P(u)],
// P(s)=s^(s>>1)^((s&1)*0x300). Table index j: lane=j&63, r=(j>>6)&3, Wj=j>>8;
// entry is for position s = (Wj<<8)|(lane<<2)|r  (Wj bits = (x8,x9)).
__global__ void precompute_kernel(const float* __restrict__ params, float2* __restrict__ tab) {
    const int j = blockIdx.x * 256 + threadIdx.x;
    if (j < 7 * 1024) {
        const int d = j >> 10, jj = j & 1023;
        const int Wj = jj >> 8, lane = jj & 63, r = (jj >> 6) & 3;
        const int s = (Wj << 8) | (lane << 2) | r;
        const int q = s ^ (s >> 1) ^ ((s & 1) * 0x300);
        const float* thA;
        const float* thB;
        if (d < 4) {
            thA = params + (d * 6 + 3) * NW;          // rz3 of block d
            thB = params + (d * 6 + 2) * NW;          // rz2 of block d
        } else {
            const int k = d - 4;
            thA = params + ((k + 1) * 6 + 0) * NW;    // rz0 of block k+1
            thB = params + (k * 6 + 5) * NW;          // rz5 of block k
        }
        float ang = 0.f;
#pragma unroll
        for (int w = 0; w < NW; ++w) {
            ang += thA[w] * (((s >> (9 - w)) & 1) ? 0.5f : -0.5f);
            ang += thB[w] * (((q >> (9 - w)) & 1) ? 0.5f : -0.5f);
        }
        float sn, cs;
        __sincosf(ang, &sn, &cs);
        tab[j] = make_float2(cs, sn);
    } else if (j < 7 * 1024 + 80) {
        const int i = j - 7 * 1024;
        const int ry = i / NW, w = i % NW;
        const int k = ry >> 1, ii = ry & 1;
        const float* th = params + (k * 6 + (ii ? 4 : 1)) * NW;
        float sn, cs;
        __sincosf(0.5f * th[w], &sn, &cs);
        tab[7 * 1024 + i] = make_float2(cs, sn);
    }
}

// ---------------- main kernel: 2 waves = 1 sample, 8 amps/lane ----
// Element position s = x9..x0:
//   x0=u0 x1=u1 (reg bits) | x2..x7 = lane bits l0..l5 | x8=u2 (reg) | x9=WAVE bit W
// Wire w at position 9-w:
//   w9:u0 w8:u1 w7:l0(xor1 DPP) w6:l1(xor2 DPP) w5:l2(xor4 swz) w4:l3(xor8 DPP)
//   w3:l4(xor16 swz) w2:l5(xor32 shfl) w1:u2 | w0:WAVE (fused into LDS perm phase)
// Perm semantics (verified vs the working 1-wave kernel): new[y] = old[P(y)],
//   P(y)_i = y_i^y_{i+1} (i<8), P(y)_8 = y8^y9^y0, P(y)_9 = y9^y0.
// LDS idx(x) = ((x>>2)&63) | (x0<<6) | (x1<<7) | (x8<<8) | (x9<<9).
// Gather src for dest (W,lane,u): x = P(y) =>
//   base(u=0): bits0..5 = l0^l1,l1^l2,l2^l3,l3^l4,l4^l5,l5; bit7=l0; bit8=bit9=W.
//   masks: u0 flips {x0,x8,x9}=0x340; u1 flips {x0,x1}=0x0C0; u2 flips {x7,x8}=0x120.
// Fused w0 butterfly at src: val = c*A[si] + sw*A[si^0x200], sign + iff src_x9=1,
//   src_x9 = W ^ u0.

#define DPP_STAGE(CTRL, CW, BIT) do {                                          \
    const float2 cw_ = (CW);                                                   \
    const float ss_ = (lane & (BIT)) ? cw_.y : -cw_.y;                         \
    _Pragma("unroll")                                                          \
    for (int u_ = 0; u_ < 8; ++u_) {                                           \
        v2f p_;                                                                \
        p_.x = fdpp<CTRL>(st[u_].x);                                           \
        p_.y = fdpp<CTRL>(st[u_].y);                                           \
        st[u_] = cw_.x * st[u_] + ss_ * p_;                                    \
    }                                                                          \
} while (0)

#define SWZ_STAGE(PAT, CW, BIT) do {                                           \
    const float2 cw_ = (CW);                                                   \
    const float ss_ = (lane & (BIT)) ? cw_.y : -cw_.y;                         \
    v2f p_[8];                                                                 \
    _Pragma("unroll")                                                          \
    for (int u_ = 0; u_ < 8; ++u_) {                                           \
        p_[u_].x = fswz<PAT>(st[u_].x);                                        \
        p_[u_].y = fswz<PAT>(st[u_].y);                                        \
    }                                                                          \
    _Pragma("unroll")                                                          \
    for (int u_ = 0; u_ < 8; ++u_) st[u_] = cw_.x * st[u_] + ss_ * p_[u_];     \
} while (0)

#define X32_STAGE(CW) do {                                                     \
    const float2 cw_ = (CW);                                                   \
    const float ss_ = (lane & 32) ? cw_.y : -cw_.y;                            \
    v2f p_[8];                                                                 \
    _Pragma("unroll")                                                          \
    for (int u_ = 0; u_ < 8; ++u_) {                                           \
        p_[u_].x = __shfl_xor(st[u_].x, 32, 64);                               \
        p_[u_].y = __shfl_xor(st[u_].y, 32, 64);                               \
    }                                                                          \
    _Pragma("unroll")                                                          \
    for (int u_ = 0; u_ < 8; ++u_) st[u_] = cw_.x * st[u_] + ss_ * p_[u_];     \
} while (0)

__global__ __launch_bounds__(128, 4) void qsim_kernel(const float* __restrict__ x,
                                                      const float2* __restrict__ tab,
                                                      float* __restrict__ out) {
    __shared__ v2f ex[2][1024];
    __shared__ float sred[2][NW];

    const int t    = threadIdx.x;
    const int W    = t >> 6;                 // wave bit = position x9 (wire 0)
    const int lane = t & 63;
    const int b    = blockIdx.x;             // one sample per 2-wave block
    const float2* ry_tab = tab + 7 * 1024;

    const int l0 = lane & 1, l1 = (lane >> 1) & 1, l2 = (lane >> 2) & 1,
              l3 = (lane >> 3) & 1, l4 = (lane >> 4) & 1, l5 = (lane >> 5) & 1;

    // ---- gather base (u=0), src = P(dest): pairwise XORs ----
    const int base = (l0 ^ l1) | ((l1 ^ l2) << 1) | ((l2 ^ l3) << 2)
                   | ((l3 ^ l4) << 3) | ((l4 ^ l5) << 4) | (l5 << 5)
                   | (l0 << 7) | (W << 8) | (W << 9);
    const int widx = lane | (W << 9);        // own write slot (idx space, +u<<6)

    v2f st[8];
    float2 xp[8];
    float2 tq[8];
    int bs = 0;

    // x-phase e^{iA_x(s)} per register
    {
        const float* xb = x + b * NW;
        float xv[NW];
#pragma unroll
        for (int w = 0; w < NW; ++w) xv[w] = xb[w];
        float A = 0.f;
#pragma unroll
        for (int w = 0; w < NW; ++w) A += xv[w];
        float hb = -0.5f * A;
        if (l0) hb += xv[7];
        if (l1) hb += xv[6];
        if (l2) hb += xv[5];
        if (l3) hb += xv[4];
        if (l4) hb += xv[3];
        if (l5) hb += xv[2];
        if (W)  hb += xv[0];
#pragma unroll
        for (int u = 0; u < 8; ++u) {
            float ang = hb;
            if (u & 1) ang += xv[9];
            if (u & 2) ang += xv[8];
            if (u & 4) ang += xv[1];
            float sn, cs;
            __sincosf(ang, &sn, &cs);
            xp[u] = make_float2(cs, sn);
        }
    }

    // prefetch folded-diag entries: tab[(d<<10) + lane + u0<<6 + u1<<7 + u2<<8 + W<<9]
    auto pre = [&](int d) {
        const float2* tb = tab + (d << 10) + lane + (W << 9);
#pragma unroll
        for (int u = 0; u < 8; ++u)
            tq[u] = tb[((u & 3) << 6) | (((u >> 2) & 1) << 8)];
    };

    // analytic init: product state after full ry(0); wire0 factor from W
    auto initC = [&]() {
        const float2 r9 = ry_tab[9], r8 = ry_tab[8], r7 = ry_tab[7], r6 = ry_tab[6],
                     r5 = ry_tab[5], r4 = ry_tab[4], r3 = ry_tab[3], r2 = ry_tab[2],
                     r1 = ry_tab[1], r0 = ry_tab[0];
        float P6 = (l0 ? r7.y : r7.x) * (l1 ? r6.y : r6.x) * (l2 ? r5.y : r5.x)
                 * (l3 ? r4.y : r4.x) * (l4 ? r3.y : r3.x) * (l5 ? r2.y : r2.x);
        P6 *= (W ? r0.y : r0.x);
#pragma unroll
        for (int u = 0; u < 8; ++u) {
            float v = P6 * ((u & 1) ? r9.y : r9.x) * ((u & 2) ? r8.y : r8.x)
                         * ((u & 4) ? r1.y : r1.x);
            st[u] = (v2f){v, 0.f};
        }
    };

    // register-local butterfly on reg-bit m
    auto bflyL = [&](float2 cw, int m) {
#pragma unroll
        for (int u = 0; u < 8; ++u)
            if (!(u & m)) {
                const int v = u | m;
                const v2f a = st[u];
                st[u] = cw.x * a - cw.y * st[v];
                st[v] = cw.y * a + cw.x * st[v];
            }
    };

    // 9 wave-local RY stages (w0 deferred to the fused LDS phase)
    auto ry = [&](int ridx) {
        const float2* rt = ry_tab + ridx * NW;
        bflyL(rt[9], 1);                 // w9: u0
        bflyL(rt[8], 2);                 // w8: u1
        bflyL(rt[1], 4);                 // w1: u2
        DPP_STAGE(0xB1, rt[7], 1);       // w7: l0 xor1
        DPP_STAGE(0x4E, rt[6], 2);       // w6: l1 xor2
        SWZ_STAGE(0x101F, rt[5], 4);     // w5: l2 xor4
        DPP_STAGE(0x128, rt[4], 8);      // w4: l3 xor8
        SWZ_STAGE(0x401F, rt[3], 16);    // w3: l4 xor16
        X32_STAGE(rt[2]);                // w2: l5 xor32
    };

    // fused: w0 butterfly (coeff cw0) + perm + diag (mode1 also x-phase)
    auto permFuse = [&](int mode, float2 cw0, bool withB) {
        v2f* B = ex[bs]; bs ^= 1;
#pragma unroll
        for (int u = 0; u < 8; ++u) B[widx + (u << 6)] = st[u];
        __syncthreads();
        const float sb = W ? cw0.y : -cw0.y;       // src x9 = W ^ u0
        constexpr int msk[8] = {0x000, 0x340, 0x0C0, 0x380, 0x120, 0x260, 0x1E0, 0x2A0};
        v2f ns[8];
#pragma unroll
        for (int u = 0; u < 8; ++u) {
            const int si = base ^ msk[u];
            const v2f a = B[si];
            if (withB) {
                const v2f p = B[si ^ 0x200];
                const float sw = (u & 1) ? -sb : sb;
                ns[u] = cw0.x * a + sw * p;
            } else {
                ns[u] = a;
            }
        }
#pragma unroll
        for (int u = 0; u < 8; ++u) {
            float cx = tq[u].x, cy = tq[u].y;
            if (mode) {
                const float tx = cx, ty = cy;
                cx = tx * xp[u].x - ty * xp[u].y;
                cy = tx * xp[u].y + ty * xp[u].x;
            }
            st[u] = (v2f){cx * ns[u].x - cy * ns[u].y,
                          cy * ns[u].x + cx * ns[u].y};
        }
    };

    // standalone w0 cross-wave butterfly (after ry(7), no perm follows)
    auto w0x = [&](float2 cw0) {
        v2f* B = ex[bs]; bs ^= 1;
#pragma unroll
        for (int u = 0; u < 8; ++u) B[widx + (u << 6)] = st[u];
        __syncthreads();
        const float sw = W ? cw0.y : -cw0.y;
#pragma unroll
        for (int u = 0; u < 8; ++u) {
            const v2f p = B[(widx ^ 0x200) + (u << 6)];
            st[u] = cw0.x * st[u] + sw * p;
        }
    };

#pragma unroll 1
    for (int k = 0; k < 4; ++k) {
        pre(k);                                          // T1[k]
        if (k == 0) initC();
        else        ry(2 * k);
        permFuse(0, ry_tab[(2 * k) * NW], k != 0);       // w0(2k) + perm + rz2.P*rz3
        if (k < 3) pre(4 + k);                           // T2[k]
        ry(2 * k + 1);
        if (k < 3) permFuse(1, ry_tab[(2 * k + 1) * NW], true);  // w0 + perm + T2*enc
        else       w0x(ry_tab[7 * NW]);                  // k==3: bare w0 butterfly
        // k==3: rz5 pure phase (dropped); final perm folded into epilogue signs.
    }

    // ---- epilogue: out[w] = sum_e (-1)^{P^{-1}(e)_{9-w}} |st(e)|^2
    // e-bits: e0=u0 e1=u1 e2..e7=l0..l5 e8=u2 e9=W.
    // P^{-1}: x8=e8^e9; x_j = e_j^..^e7^e8^e9 (j<=7); x9 = e0^..^e8 (no e9).
    float pr[8];
#pragma unroll
    for (int u = 0; u < 8; ++u) pr[u] = st[u].x * st[u].x + st[u].y * st[u].y;

    float q0[2], q1[2], q2[2];
#pragma unroll
    for (int g = 0; g < 2; ++g) {
        const float a = pr[4 * g] + pr[4 * g + 1], bb = pr[4 * g + 2] + pr[4 * g + 3];
        const float c = pr[4 * g] - pr[4 * g + 1], d = pr[4 * g + 2] - pr[4 * g + 3];
        q0[g] = a + bb;   // sum over u0,u1
        q1[g] = a - bb;   // (-1)^{u1}
        q2[g] = c - d;    // (-1)^{u0^u1}
    }
    const float S0 = q0[0] - q0[1];          // (-1)^{u2}
    const float S1 = q1[0] - q1[1];          // (-1)^{u1^u2}
    const float S2 = q2[0] - q2[1];          // (-1)^{u0^u1^u2}
    const float sg = W ? -1.f : 1.f;         // (-1)^{e9}
    const float R23   = sg * S0;             // (-1)^{e8^e9}
    const float R123  = sg * S1;             // (-1)^{e1... (u1^u2^W)}
    const float R0123 = sg * S2;             // (-1)^{u0^u1^u2^W}
    const float R012  = S2;                  // (-1)^{u0^u1^u2}

    // lane suffix parities over l5..l0 (= e7..e2)
    const int P5 = l5, P4 = l4 ^ P5, P3 = l3 ^ P4, P2 = l2 ^ P3, P1 = l1 ^ P2, P0 = l0 ^ P1;

    float acc[NW];
    acc[0] = P0 ? -R012 : R012;    // x9
    acc[1] = R23;                  // x8
    acc[2] = P5 ? -R23 : R23;      // x7
    acc[3] = P4 ? -R23 : R23;      // x6
    acc[4] = P3 ? -R23 : R23;      // x5
    acc[5] = P2 ? -R23 : R23;      // x4
    acc[6] = P1 ? -R23 : R23;      // x3
    acc[7] = P0 ? -R23 : R23;      // x2
    acc[8] = P0 ? -R123 : R123;    // x1
    acc[9] = P0 ? -R0123 : R0123;  // x0

#pragma unroll
    for (int w = 0; w < NW; ++w) {
        float a = acc[w];
        a += fdpp<0xB1>(a);
        a += fdpp<0x4E>(a);
        a += fswz<0x101F>(a);
        a += fdpp<0x128>(a);
        a += fswz<0x401F>(a);
        a += __shfl_xor(a, 32, 64);
        acc[w] = a;
    }
    if (lane == 0) {
#pragma unroll
        for (int w = 0; w < NW; ++w) sred[W][w] = acc[w];
    }
    __syncthreads();
    if (t < NW) out[b * NW + t] = sred[0][t] + sred[1][t];
}

extern "C" void kernel_launch(void* const* d_in, const int* in_sizes, int n_in,
                              void* d_out, int out_size, void* d_ws, size_t ws_size,
                              hipStream_t stream) {
    const float* x      = (const float*)d_in[0];   // (2048, 10)
    const float* params = (const float*)d_in[1];   // (4, 6, 10)
    float* out          = (float*)d_out;           // (1, 2048, 10)
    float2* tab         = (float2*)d_ws;           // 7*1024+80 float2 = 57 KB
    (void)in_sizes; (void)n_in; (void)out_size; (void)ws_size;
    precompute_kernel<<<29, 256, 0, stream>>>(params, tab);
    qsim_kernel<<<2048, 128, 0, stream>>>(x, tab, out);
}